// Round 3
// baseline (141.767 us; speedup 1.0000x reference)
//
#include <hip/hip_runtime.h>

#define IMG 8
#define LH 150
#define LQ 10
#define KITER 10   // 9 scan steps + final conv (v-update on last iter unused)

// Packed fp32 FMA (VOP3P) — gfx950's 157.3 TF fp32 peak is only reachable via
// v_pk_fma_f32 (2 f32 lanes per issue slot). Compiler won't form it from
// scalar fmaf, so emit directly. Pure op: no volatile, scheduler may move it.
__device__ __forceinline__ float2 pk_fma(float2 a, float2 b, float2 c) {
    float2 d;
    asm("v_pk_fma_f32 %0, %1, %2, %3" : "=v"(d) : "v"(a), "v"(b), "v"(c));
    return d;
}

// ---------------------------------------------------------------------------
// Pre-kernel: collapse h/r convs (exact — no nonlinearity between h and r).
//   ws[t]  = sum_c Wr[c] * Wh[c, t]   (t = 0..8)
//   ws[9]  = sum_c Wr[c] * bh[c]
// ---------------------------------------------------------------------------
__global__ void weff_kernel(const float* __restrict__ Wh,
                            const float* __restrict__ bh,
                            const float* __restrict__ Wr,
                            float* __restrict__ ws) {
    const int wv = threadIdx.x >> 6;   // 0..9 (wave-uniform)
    const int lane = threadIdx.x & 63;
    float partial = 0.f;
    for (int c = lane; c < LH; c += 64) {
        const float wr = Wr[c];
        partial += wr * ((wv < 9) ? Wh[c * 9 + wv] : bh[c]);
    }
    #pragma unroll
    for (int off = 32; off > 0; off >>= 1)
        partial += __shfl_xor(partial, off);   // full wave active
    if (lane == 0) ws[wv] = partial;
}

// ---------------------------------------------------------------------------
// Main kernel: one wave per batch item, lane = pixel (y = lane>>3, x = lane&7).
// All shuffles execute at full-wave convergence; zero-padding applied by
// mask-multiply AFTER the shuffle (bpermute from inactive source lane = bug).
// Inner 10x9 matvec packed into float2 over output-channel pairs.
// ---------------------------------------------------------------------------
__global__ __launch_bounds__(256) void vin_kernel(
    const float* __restrict__ S,
    const float* __restrict__ Wq,
    const float* __restrict__ w,
    const float* __restrict__ Wfc,
    const float* __restrict__ ws,
    float* __restrict__ out,
    int B) {
    const int wave = threadIdx.x >> 6;
    const int lane = threadIdx.x & 63;
    const int b = blockIdx.x * 4 + wave;
    if (b >= B) return;                       // wave-uniform

    const int y = lane >> 3, x = lane & 7;

    const float* Sb = S + (long)b * (IMG * IMG + 2);
    const float X = Sb[lane];
    const int s1 = (int)Sb[IMG * IMG];
    const int s2 = (int)Sb[IMG * IMG + 1];
    const int sel_lane = s1 * 8 + s2;

    // 3x3 neighbor lane indices + zero-pad masks.
    int   nidx[9];
    float nmsk[9];
    #pragma unroll
    for (int t = 0; t < 9; ++t) {
        const int dy = t / 3 - 1, dx = t % 3 - 1;
        const int ny = y + dy, nx = x + dx;
        const bool v = ((unsigned)ny < 8u) && ((unsigned)nx < 8u);
        nidx[t] = v ? (ny * 8 + nx) : 0;
        nmsk[t] = v ? 1.f : 0.f;
    }

    // r = conv(X, Weff, pad=1) + beff   (mask folded into per-lane Weff copy)
    float r = ws[9];
    #pragma unroll
    for (int t = 0; t < 9; ++t) {
        const float wm = ws[t] * nmsk[t];
        r = fmaf(wm, __shfl(X, nidx[t]), r);
    }

    // rn2[t] = broadcast pair of masked r-neighbor (shuffle at full convergence)
    float2 rn2[9];
    #pragma unroll
    for (int t = 0; t < 9; ++t) {
        const float rv = __shfl(r, nidx[t]) * nmsk[t];
        rn2[t].x = rv; rn2[t].y = rv;
    }

    // qr2[j] = packed (o=2j, 2j+1) of conv(r, Wq, pad=1) — loop-invariant.
    float2 qr2[5];
    #pragma unroll
    for (int j = 0; j < 5; ++j) { qr2[j].x = 0.f; qr2[j].y = 0.f; }
    #pragma unroll
    for (int t = 0; t < 9; ++t) {
        #pragma unroll
        for (int j = 0; j < 5; ++j) {
            float2 wq2; wq2.x = Wq[(2 * j) * 9 + t]; wq2.y = Wq[(2 * j + 1) * 9 + t];
            qr2[j] = pk_fma(rn2[t], wq2, qr2[j]);
        }
    }

    // w (scan-conv weights) resident as packed pairs.
    float2 ww2[5][9];
    #pragma unroll
    for (int j = 0; j < 5; ++j)
        #pragma unroll
        for (int t = 0; t < 9; ++t) {
            ww2[j][t].x = w[(2 * j) * 9 + t];
            ww2[j][t].y = w[(2 * j + 1) * 9 + t];
        }

    // v0 = max_o qr[o]
    float v;
    {
        const float m0 = fmaxf(fmaxf(qr2[0].x, qr2[0].y), fmaxf(qr2[1].x, qr2[1].y));
        const float m1 = fmaxf(fmaxf(qr2[2].x, qr2[2].y), fmaxf(qr2[3].x, qr2[3].y));
        const float m2 = fmaxf(qr2[4].x, qr2[4].y);
        v = fmaxf(fmaxf(m0, m1), m2);
    }

    // Value iteration: 45 pk_fma per step (10x9 matvec over output pairs).
    float2 q2[5];
    for (int k = 0; k < KITER; ++k) {
        float2 vn2[9];
        #pragma unroll
        for (int t = 0; t < 9; ++t) {
            const float vv = __shfl(v, nidx[t]) * nmsk[t];   // full convergence
            vn2[t].x = vv; vn2[t].y = vv;
        }
        #pragma unroll
        for (int j = 0; j < 5; ++j) q2[j] = qr2[j];
        #pragma unroll
        for (int t = 0; t < 9; ++t)
            #pragma unroll
            for (int j = 0; j < 5; ++j)
                q2[j] = pk_fma(vn2[t], ww2[j][t], q2[j]);
        const float m0 = fmaxf(fmaxf(q2[0].x, q2[0].y), fmaxf(q2[1].x, q2[1].y));
        const float m1 = fmaxf(fmaxf(q2[2].x, q2[2].y), fmaxf(q2[3].x, q2[3].y));
        const float m2 = fmaxf(q2[4].x, q2[4].y);
        v = fmaxf(fmaxf(m0, m1), m2);      // unused after last iter (harmless)
    }

    // q_sel broadcast from sel_lane (before divergence); lanes 0..7 emit logits.
    float qsel[LQ];
    #pragma unroll
    for (int j = 0; j < 5; ++j) {
        qsel[2 * j]     = __shfl(q2[j].x, sel_lane);
        qsel[2 * j + 1] = __shfl(q2[j].y, sel_lane);
    }

    if (lane < 8) {
        float acc = 0.f;
        #pragma unroll
        for (int o = 0; o < LQ; ++o) acc = fmaf(qsel[o], Wfc[lane * LQ + o], acc);
        out[(long)b * 8 + lane] = acc;
    }
}

extern "C" void kernel_launch(void* const* d_in, const int* in_sizes, int n_in,
                              void* d_out, int out_size, void* d_ws, size_t ws_size,
                              hipStream_t stream) {
    const float* S   = (const float*)d_in[0];
    const float* Wh  = (const float*)d_in[1];
    const float* bh  = (const float*)d_in[2];
    const float* Wr  = (const float*)d_in[3];
    const float* Wq  = (const float*)d_in[4];
    const float* w   = (const float*)d_in[5];
    const float* Wfc = (const float*)d_in[6];
    float* out = (float*)d_out;
    float* ws  = (float*)d_ws;

    const int B = in_sizes[0] / (IMG * IMG + 2);

    weff_kernel<<<1, 640, 0, stream>>>(Wh, bh, Wr, ws);

    const int waves_per_block = 4;  // 256 threads
    const int grid = (B + waves_per_block - 1) / waves_per_block;
    vin_kernel<<<grid, 256, 0, stream>>>(S, Wq, w, Wfc, ws, out, B);
}

// Round 5
// 101.360 us; speedup vs baseline: 1.3986x; 1.3986x over previous
//
#include <hip/hip_runtime.h>

#define IMG 8
#define LH 150
#define LQ 10
#define KITER 10   // 9 scan steps + final conv (v-update on last iter unused)
#define ROW (IMG * IMG + 2)   // 66 floats per batch row

// ds_bpermute with precomputed BYTE address (hoists the <<2 out of hot loops).
// Must be executed at full-wave convergence (inactive source lane => garbage).
__device__ __forceinline__ float bperm(int byte_addr, float v) {
    return __builtin_bit_cast(float,
        __builtin_amdgcn_ds_bpermute(byte_addr, __builtin_bit_cast(int, v)));
}

__device__ __forceinline__ float max10(const float q[LQ]) {
    // max3-shaped tree: 4x v_max3 + 1x v_max
    const float g0 = fmaxf(fmaxf(q[0], q[1]), q[2]);
    const float g1 = fmaxf(fmaxf(q[3], q[4]), q[5]);
    const float g2 = fmaxf(fmaxf(q[6], q[7]), q[8]);
    return fmaxf(fmaxf(g0, g1), fmaxf(g2, q[9]));
}

// ---------------------------------------------------------------------------
// Pre-kernel: collapse h/r convs (exact — no nonlinearity between h and r).
//   ws[t] = sum_c Wr[c] * Wh[c, t]  (t=0..8),  ws[9] = sum_c Wr[c] * bh[c]
// ---------------------------------------------------------------------------
__global__ void weff_kernel(const float* __restrict__ Wh,
                            const float* __restrict__ bh,
                            const float* __restrict__ Wr,
                            float* __restrict__ ws) {
    const int wv = threadIdx.x >> 6;   // 0..9 (wave-uniform)
    const int lane = threadIdx.x & 63;
    float partial = 0.f;
    for (int c = lane; c < LH; c += 64) {
        const float wr = Wr[c];
        partial += wr * ((wv < 9) ? Wh[c * 9 + wv] : bh[c]);
    }
    #pragma unroll
    for (int off = 32; off > 0; off >>= 1)
        partial += __shfl_xor(partial, off);   // full wave active
    if (lane == 0) ws[wv] = partial;
}

// ---------------------------------------------------------------------------
// Main kernel: one wave handles TWO batch items (two independent dependency
// chains to hide bpermute/VALU latency); lane = pixel (y=lane>>3, x=lane&7).
// All shuffles at full-wave convergence; zero-pad via mask-mul after shuffle.
// ---------------------------------------------------------------------------
__global__ __launch_bounds__(256) void vin_kernel(
    const float* __restrict__ S,
    const float* __restrict__ Wq,
    const float* __restrict__ w,
    const float* __restrict__ Wfc,
    const float* __restrict__ ws,
    float* __restrict__ out,
    int B) {
    const int wave = threadIdx.x >> 6;
    const int lane = threadIdx.x & 63;
    const long b0 = (long)(blockIdx.x * 4 + wave) * 2;   // items b0, b0+1
    if (b0 >= B) return;                                  // wave-uniform

    const int y = lane >> 3, x = lane & 7;

    // 3x3 neighbor byte-addresses + zero-pad masks (shared by both items).
    int   addr[9];
    float msk[9];
    #pragma unroll
    for (int t = 0; t < 9; ++t) {
        const int dy = t / 3 - 1, dx = t % 3 - 1;
        const int ny = y + dy, nx = x + dx;
        const bool v = ((unsigned)ny < 8u) && ((unsigned)nx < 8u);
        addr[t] = (v ? (ny * 8 + nx) : 0) << 2;
        msk[t]  = v ? 1.f : 0.f;
    }

    const float* S0 = S + b0 * ROW;
    const float X0 = S0[lane];
    const float X1 = S0[ROW + lane];
    // (s1,s2) live at row offsets 64,65 of each item's ROW=66 stride.
    const int sel0 = (int)S0[IMG * IMG] * 8 + (int)S0[IMG * IMG + 1];
    const int sel1 = (int)S0[ROW + IMG * IMG] * 8 + (int)S0[ROW + IMG * IMG + 1];

    // r = conv(X, Weff, pad=1) + beff  (mask folded into per-lane Weff copy)
    float r0 = ws[9], r1 = ws[9];
    #pragma unroll
    for (int t = 0; t < 9; ++t) {
        const float wm = ws[t] * msk[t];
        r0 = fmaf(wm, bperm(addr[t], X0), r0);
        r1 = fmaf(wm, bperm(addr[t], X1), r1);
    }

    // qr[o] = conv(r, Wq, pad=1)  — loop-invariant part of the value iteration.
    float qr0[LQ], qr1[LQ];
    #pragma unroll
    for (int t = 0; t < 9; ++t) {
        const float a0 = bperm(addr[t], r0) * msk[t];
        const float a1 = bperm(addr[t], r1) * msk[t];
        #pragma unroll
        for (int o = 0; o < LQ; ++o) {
            const float wq = Wq[o * 9 + t];        // wave-uniform (SGPR)
            if (t == 0) { qr0[o] = a0 * wq; qr1[o] = a1 * wq; }
            else        { qr0[o] = fmaf(a0, wq, qr0[o]);
                          qr1[o] = fmaf(a1, wq, qr1[o]); }
        }
    }

    float v0 = max10(qr0), v1 = max10(qr1);

    // Value iteration: tap-major so only one shuffled value live per tap.
    float q0[LQ], q1[LQ];
    #pragma unroll
    for (int k = 0; k < KITER; ++k) {
        #pragma unroll
        for (int t = 0; t < 9; ++t) {
            const float a0 = bperm(addr[t], v0) * msk[t];
            const float a1 = bperm(addr[t], v1) * msk[t];
            #pragma unroll
            for (int o = 0; o < LQ; ++o) {
                const float wt = w[o * 9 + t];     // wave-uniform (SGPR)
                if (t == 0) { q0[o] = fmaf(a0, wt, qr0[o]);
                              q1[o] = fmaf(a1, wt, qr1[o]); }
                else        { q0[o] = fmaf(a0, wt, q0[o]);
                              q1[o] = fmaf(a1, wt, q1[o]); }
            }
        }
        v0 = max10(q0);   // unused after last iter (harmless)
        v1 = max10(q1);
    }

    // Broadcast q at the agent position (before any divergence).
    float qs0[LQ], qs1[LQ];
    #pragma unroll
    for (int o = 0; o < LQ; ++o) {
        qs0[o] = bperm(sel0 << 2, q0[o]);
        qs1[o] = bperm(sel1 << 2, q1[o]);
    }

    // Lanes 0..7 emit item b0's logits, lanes 8..15 item b0+1's.
    // out[b0*8 + lane] covers both halves since b1 = b0 + 1.
    if (lane < 16) {
        const int row = lane & 7;
        float acc = 0.f;
        #pragma unroll
        for (int o = 0; o < LQ; ++o)
            acc = fmaf((lane < 8) ? qs0[o] : qs1[o], Wfc[row * LQ + o], acc);
        out[b0 * 8 + lane] = acc;
    }
}

extern "C" void kernel_launch(void* const* d_in, const int* in_sizes, int n_in,
                              void* d_out, int out_size, void* d_ws, size_t ws_size,
                              hipStream_t stream) {
    const float* S   = (const float*)d_in[0];
    const float* Wh  = (const float*)d_in[1];
    const float* bh  = (const float*)d_in[2];
    const float* Wr  = (const float*)d_in[3];
    const float* Wq  = (const float*)d_in[4];
    const float* w   = (const float*)d_in[5];
    const float* Wfc = (const float*)d_in[6];
    float* out = (float*)d_out;
    float* ws  = (float*)d_ws;

    const int B = in_sizes[0] / ROW;

    weff_kernel<<<1, 640, 0, stream>>>(Wh, bh, Wr, ws);

    // 4 waves/block, 2 items/wave => 8 items per block.
    const int grid = (B + 7) / 8;
    vin_kernel<<<grid, 256, 0, stream>>>(S, Wq, w, Wfc, ws, out, B);
}